// Round 2
// baseline (1266.929 us; speedup 1.0000x reference)
//
#include <hip/hip_runtime.h>

#define NN 2048
#define WW 32            // u64 words per bitmask row
#define DD 512
#define MS 512           // super nodes
#define TGTM 1536        // merges = NN - MS
#define KEYMAX 0x3FFFFFu

__device__ __forceinline__ void atomicMin64(unsigned long long* p, unsigned long long v){
  unsigned long long old = *p;
  while (v < old){
    unsigned long long assumed = old;
    old = atomicCAS(p, assumed, v);
    if (old == assumed) break;
  }
}

// Build 2048-bit adjacency bitmasks, degrees, and init component labels.
__global__ void k_build_bits(const float* __restrict__ A, unsigned long long* __restrict__ bits,
                             unsigned* __restrict__ deg, unsigned* __restrict__ comp){
  int gid = blockIdx.x*blockDim.x + threadIdx.x;   // NN*WW threads
  int i = gid >> 5, w = gid & 31;
  const float* row = A + ((size_t)i << 11) + (w << 6);
  unsigned long long m = 0ull;
  for (int k = 0; k < 64; ++k) if (row[k] > 0.0f) m |= (1ull << k);
  bits[((size_t)i << 5) + w] = m;
  atomicAdd(&deg[i], (unsigned)__popcll(m));
  if (gid < NN) comp[gid] = (unsigned)gid;
}

// Full symmetric key matrix: key22 = round(inter * 2^22 / union), exact int math.
__global__ void k_keymat(const unsigned long long* __restrict__ bits,
                         const unsigned* __restrict__ deg, unsigned* __restrict__ keyM){
  __shared__ unsigned long long bi[64][33];   // +1 pad: avoid 32-way LDS bank conflicts
  __shared__ unsigned long long bj[64][33];
  __shared__ unsigned degi[64], degj[64];
  int ib = blockIdx.x, jb = blockIdx.y;
  int t = threadIdx.x;
  for (int idx = t; idx < 64*32; idx += 256){
    int r = idx >> 5, w = idx & 31;
    bi[r][w] = bits[(((size_t)(ib*64 + r)) << 5) + w];
    bj[r][w] = bits[(((size_t)(jb*64 + r)) << 5) + w];
  }
  if (t < 64){ degi[t] = deg[ib*64 + t]; degj[t] = deg[jb*64 + t]; }
  __syncthreads();
  for (int p = t; p < 4096; p += 256){
    int ii = p >> 6, jj = p & 63;
    int i = ib*64 + ii, j = jb*64 + jj;
    unsigned key = 0u;
    if (i != j){
      unsigned inter = 0;
      #pragma unroll
      for (int w = 0; w < 32; ++w) inter += (unsigned)__popcll(bi[ii][w] & bj[jj][w]);
      unsigned b = degi[ii] + degj[jj] - inter;
      if (b != 0u){
        unsigned long long num = (((unsigned long long)inter) << 22) + (b >> 1);
        unsigned long long q = num / b;
        key = (q > (unsigned long long)KEYMAX) ? KEYMAX : (unsigned)q;
      }
    }
    keyM[((size_t)i << 11) + j] = key;
  }
}

// Per-node best outgoing edge (min 44-bit val) — one wave per row.
// Early-exits once the spanning tree is complete (msf_cnt == NN-1).
__global__ void k_best_node(const unsigned* __restrict__ keyM, const unsigned* __restrict__ comp,
                            unsigned long long* __restrict__ node_best,
                            const unsigned* __restrict__ msf_cnt){
  if (msf_cnt[0] >= (unsigned)(NN-1)) return;
  int gt = blockIdx.x*blockDim.x + threadIdx.x;
  int i = gt >> 6, lane = gt & 63;
  unsigned ci = comp[i];
  const unsigned* row = keyM + ((size_t)i << 11);
  unsigned long long best = ~0ull;
  for (int j = lane; j < NN; j += 64){
    if (j == i) continue;
    if (comp[j] == ci) continue;
    unsigned kp = KEYMAX - row[j];
    unsigned a  = (i < j) ? (unsigned)i : (unsigned)j;
    unsigned b2 = (i < j) ? (unsigned)j : (unsigned)i;
    unsigned long long v = (((unsigned long long)kp) << 22) | (((unsigned long long)a) << 11) | b2;
    if (v < best) best = v;
  }
  for (int off = 32; off; off >>= 1){
    unsigned long long o = __shfl_xor(best, off);
    if (o < best) best = o;
  }
  if (lane == 0) node_best[i] = best;
}

// One Boruvka round: per-component best, hook, 2-cycle break, collect MSF edges,
// pointer-double, relabel. Single block.
__global__ void k_merge(const unsigned long long* __restrict__ node_best,
                        unsigned* __restrict__ comp,
                        unsigned long long* __restrict__ msf, unsigned* __restrict__ msf_cnt){
  if (msf_cnt[0] >= (unsigned)(NN-1)) return;
  __shared__ unsigned long long cbest[NN];
  __shared__ unsigned nxtA[NN], nxtB[NN];
  int t = threadIdx.x;
  for (int c = t; c < NN; c += 256) cbest[c] = ~0ull;
  __syncthreads();
  for (int i = t; i < NN; i += 256) atomicMin64(&cbest[comp[i]], node_best[i]);
  __syncthreads();
  for (int c = t; c < NN; c += 256) nxtA[c] = (unsigned)c;
  __syncthreads();
  for (int c = t; c < NN; c += 256){
    unsigned long long v = cbest[c];
    if (v != ~0ull){
      unsigned a = (unsigned)((v >> 11) & 2047u), b = (unsigned)(v & 2047u);
      unsigned la = comp[a], lb = comp[b];
      if (la != lb) nxtA[c] = (la == (unsigned)c) ? lb : la;
    }
  }
  __syncthreads();
  for (int c = t; c < NN; c += 256){
    unsigned o = nxtA[c];
    if (o != (unsigned)c && nxtA[o] == (unsigned)c && (unsigned)c < o) nxtA[c] = (unsigned)c;
  }
  __syncthreads();
  for (int c = t; c < NN; c += 256){
    if (nxtA[c] != (unsigned)c){
      unsigned idx = atomicAdd(msf_cnt, 1u);
      if (idx < (unsigned)NN) msf[idx] = cbest[c];
    }
  }
  __syncthreads();
  unsigned* s1 = nxtA; unsigned* s2 = nxtB;
  for (int r = 0; r < 11; ++r){
    for (int c = t; c < NN; c += 256) s2[c] = s1[s1[c]];
    __syncthreads();
    unsigned* tmp = s1; s1 = s2; s2 = tmp;
  }
  for (int i = t; i < NN; i += 256) comp[i] = s1[comp[i]];
}

// Sort the 2047 MSF edges, take first TGTM, connected components, labels,
// sizes/scale, cluster member lists (offs + memb).
__global__ void k_final(const unsigned long long* __restrict__ msf, const unsigned* __restrict__ msf_cnt,
                        unsigned* __restrict__ labels_g, float* __restrict__ scale_g,
                        unsigned* __restrict__ offs_g, unsigned* __restrict__ memb_g){
  __shared__ unsigned long long ed[NN];      // later reused as fo/plab
  __shared__ unsigned long long cbest[NN];   // later reused as sizes/scanT
  __shared__ unsigned lab[NN], nxtA[NN], nxtB[NN];
  int t = threadIdx.x;
  unsigned cnt = msf_cnt[0]; if (cnt > (unsigned)NN) cnt = NN;
  for (int i = t; i < NN; i += 256) ed[i] = (i < (int)cnt) ? msf[i] : ~0ull;
  __syncthreads();
  // bitonic sort ascending (44-bit vals unique; pads ~0 sort last)
  for (unsigned k = 2; k <= (unsigned)NN; k <<= 1)
    for (unsigned j = k >> 1; j > 0; j >>= 1){
      for (int i = t; i < NN; i += 256){
        unsigned l = ((unsigned)i) ^ j;
        if (l > (unsigned)i){
          bool up = ((((unsigned)i) & k) == 0u);
          unsigned long long x = ed[i], y = ed[l];
          if ((x > y) == up){ ed[i] = y; ed[l] = x; }
        }
      }
      __syncthreads();
    }
  // CC of first TGTM edges via Boruvka-style hooking (guaranteed <=11 rounds)
  for (int i = t; i < NN; i += 256) lab[i] = (unsigned)i;
  __syncthreads();
  for (int round = 0; round < 11; ++round){
    for (int c = t; c < NN; c += 256) cbest[c] = ~0ull;
    __syncthreads();
    for (int e = t; e < TGTM; e += 256){
      unsigned long long v = ed[e];
      unsigned a = (unsigned)((v >> 11) & 2047u), b = (unsigned)(v & 2047u);
      unsigned la = lab[a], lb = lab[b];
      if (la != lb){ atomicMin64(&cbest[la], v); atomicMin64(&cbest[lb], v); }
    }
    __syncthreads();
    for (int c = t; c < NN; c += 256) nxtA[c] = (unsigned)c;
    __syncthreads();
    for (int c = t; c < NN; c += 256){
      unsigned long long v = cbest[c];
      if (v != ~0ull){
        unsigned a = (unsigned)((v >> 11) & 2047u), b = (unsigned)(v & 2047u);
        unsigned la = lab[a], lb = lab[b];
        if (la != lb) nxtA[c] = (la == (unsigned)c) ? lb : la;
      }
    }
    __syncthreads();
    for (int c = t; c < NN; c += 256){
      unsigned o = nxtA[c];
      if (o != (unsigned)c && nxtA[o] == (unsigned)c && (unsigned)c < o) nxtA[c] = (unsigned)c;
    }
    __syncthreads();
    unsigned* s1 = nxtA; unsigned* s2 = nxtB;
    for (int r = 0; r < 11; ++r){
      for (int c = t; c < NN; c += 256) s2[c] = s1[s1[c]];
      __syncthreads();
      unsigned* tmp = s1; s1 = s2; s2 = tmp;
    }
    for (int i = t; i < NN; i += 256) lab[i] = s1[lab[i]];
    __syncthreads();
  }
  // labels = rank of class by min member; sizes; scale; member lists
  unsigned* fo    = (unsigned*)ed;
  unsigned* plab  = ((unsigned*)ed) + NN;
  unsigned* sizes = (unsigned*)cbest;
  unsigned* scanT = ((unsigned*)cbest) + 1024;
  for (int i = t; i < NN; i += 256) fo[i] = 0xFFFFFFFFu;
  __syncthreads();
  for (int i = t; i < NN; i += 256) atomicMin(&fo[lab[i]], (unsigned)i);
  __syncthreads();
  unsigned loc[8]; unsigned s = 0; int base = t*8;
  for (int k = 0; k < 8; ++k){
    int i = base + k;
    unsigned isf = (fo[lab[i]] == (unsigned)i) ? 1u : 0u;
    loc[k] = s; s += isf;
  }
  scanT[t] = s; __syncthreads();
  for (int off = 1; off < 256; off <<= 1){
    unsigned x = (t >= off) ? scanT[t-off] : 0u;
    __syncthreads();
    scanT[t] += x;
    __syncthreads();
  }
  unsigned excl = scanT[t] - s;
  for (int k = 0; k < 8; ++k) plab[base + k] = excl + loc[k];
  __syncthreads();
  for (int c = t; c < MS; c += 256) sizes[c] = 0u;
  __syncthreads();
  for (int i = t; i < NN; i += 256){
    unsigned L = plab[fo[lab[i]]];
    labels_g[i] = L;
    if (L < (unsigned)MS) atomicAdd(&sizes[L], 1u);
  }
  __syncthreads();
  for (int c = t; c < MS; c += 256) scale_g[c] = 1.0f / sqrtf((float)sizes[c] + 1e-10f);
  // --- member lists: prefix-sum sizes -> offs, scatter node ids by label ---
  unsigned* off_l  = nxtA;          // [0..MS)
  unsigned* cursor = nxtA + 1024;   // [0..MS)
  {
    unsigned a = sizes[2*t], b = sizes[2*t + 1];
    scanT[t] = a + b; __syncthreads();
    for (int o = 1; o < 256; o <<= 1){
      unsigned x = (t >= o) ? scanT[t-o] : 0u;
      __syncthreads();
      scanT[t] += x;
      __syncthreads();
    }
    unsigned ex = scanT[t] - (a + b);
    off_l[2*t]   = ex;
    off_l[2*t+1] = ex + a;
    offs_g[2*t]   = ex;
    offs_g[2*t+1] = ex + a;
    if (t == 0) offs_g[MS] = (unsigned)NN;
  }
  __syncthreads();
  for (int c = t; c < MS; c += 256) cursor[c] = off_l[c];
  __syncthreads();
  for (int i = t; i < NN; i += 256){
    unsigned L = plab[fo[lab[i]]];
    unsigned pos = atomicAdd(&cursor[L], 1u);
    memb_g[pos] = (unsigned)i;
  }
}

__global__ void k_writeP(const unsigned* __restrict__ labels, const float* __restrict__ scale,
                         float* __restrict__ P){
  int i = blockIdx.x*blockDim.x + threadIdx.x;
  if (i < NN){ unsigned L = labels[i]; P[((size_t)i << 9) + L] = scale[L]; }
}

// X_coarse: one block per cluster; segmented sum over member rows, no atomics.
__global__ void k_coarseX(const float* __restrict__ X, const unsigned* __restrict__ offs,
                          const unsigned* __restrict__ memb, const float* __restrict__ scale,
                          float* __restrict__ Xc){
  int c = blockIdx.x, t = threadIdx.x;
  unsigned o = offs[c], e = offs[c+1];
  float sc = scale[c];
  for (int d = t; d < DD; d += 256){
    float acc = 0.0f;
    for (unsigned k = o; k < e; ++k){
      unsigned m = memb[k];                       // wave-uniform broadcast load
      acc += X[((size_t)m << 9) + d];             // coalesced across lanes
    }
    Xc[((size_t)c << 9) + d] = sc * acc;
  }
}

// A_coarse: one block per cluster; count edges to each cluster in an LDS row
// via members' adjacency bitmasks (A is binary), then write row coalesced.
__global__ void k_coarseA(const unsigned long long* __restrict__ bits,
                          const unsigned* __restrict__ labels,
                          const unsigned* __restrict__ offs, const unsigned* __restrict__ memb,
                          const float* __restrict__ scale, float* __restrict__ Ac){
  __shared__ float row[MS];
  int c = blockIdx.x, t = threadIdx.x;
  for (int j = t; j < MS; j += 256) row[j] = 0.0f;
  __syncthreads();
  unsigned o = offs[c], e = offs[c+1];
  int nm = (int)(e - o);
  for (int idx = t; idx < nm*WW; idx += 256){
    unsigned m = memb[o + (idx >> 5)];
    int w = idx & 31;
    unsigned long long word = bits[((size_t)m << 5) + w];
    while (word){
      int b = __ffsll((long long)word) - 1;
      unsigned j = (unsigned)(w*64 + b);
      atomicAdd(&row[labels[j]], 1.0f);           // LDS atomic
      word &= word - 1ull;
    }
  }
  __syncthreads();
  float sc = scale[c];
  for (int j = t; j < MS; j += 256)
    Ac[((size_t)c << 9) + j] = row[j] * sc * scale[j];
}

extern "C" void kernel_launch(void* const* d_in, const int* in_sizes, int n_in,
                              void* d_out, int out_size, void* d_ws, size_t ws_size,
                              hipStream_t stream) {
  const float* X = (const float*)d_in[0];
  const float* A = (const float*)d_in[1];
  float* out = (float*)d_out;
  char* ws = (char*)d_ws;
  // workspace layout (~16.6 MB, unchanged footprint; memb/offs overlay dead regions)
  unsigned long long* bits     = (unsigned long long*)(ws + 0x000000);  // 512 KB, live whole run
  unsigned*           deg      = (unsigned*)          (ws + 0x080000);  // 8 KB  (dead after keymat)
  unsigned*           comp     = (unsigned*)          (ws + 0x082000);  // 8 KB  (dead after merges)
  unsigned long long* nodebest = (unsigned long long*)(ws + 0x084000);  // 16 KB (dead after merges)
  unsigned long long* msf      = (unsigned long long*)(ws + 0x088000);  // 16 KB
  unsigned*           msfcnt   = (unsigned*)          (ws + 0x08C000);  // 4 B
  unsigned*           labels   = (unsigned*)          (ws + 0x08D000);  // 8 KB
  float*              scale    = (float*)             (ws + 0x08F000);  // 2 KB
  unsigned*           memb     = (unsigned*)          (ws + 0x084000);  // overlays nodebest (8 KB)
  unsigned*           offs     = (unsigned*)          (ws + 0x080000);  // overlays deg (2052 B)
  unsigned*           keyM     = (unsigned*)          (ws + 0x090000);  // 16 MB

  hipMemsetAsync(deg, 0, NN*sizeof(unsigned), stream);
  hipMemsetAsync(msfcnt, 0, sizeof(unsigned), stream);
  hipMemsetAsync(out + 2*MS*MS, 0, (size_t)NN*MS*sizeof(float), stream);  // P region only

  k_build_bits<<<(NN*WW)/256, 256, 0, stream>>>(A, bits, deg, comp);
  k_keymat<<<dim3(NN/64, NN/64), 256, 0, stream>>>(bits, deg, keyM);
  for (int r = 0; r < 11; ++r){
    k_best_node<<<(NN*64)/256, 256, 0, stream>>>(keyM, comp, nodebest, msfcnt);
    k_merge<<<1, 256, 0, stream>>>(nodebest, comp, msf, msfcnt);
  }
  k_final<<<1, 256, 0, stream>>>(msf, msfcnt, labels, scale, offs, memb);
  k_writeP<<<NN/256, 256, 0, stream>>>(labels, scale, out + 2*MS*MS);
  k_coarseX<<<MS, 256, 0, stream>>>(X, offs, memb, scale, out);
  k_coarseA<<<MS, 256, 0, stream>>>(bits, labels, offs, memb, scale, out + MS*MS);
}

// Round 4
// 613.865 us; speedup vs baseline: 2.0639x; 2.0639x over previous
//
#include <hip/hip_runtime.h>

#define NN 2048
#define WW 32            // u64 words per bitmask row
#define DD 512
#define MS 512           // super nodes
#define TGTM 1536        // merges = NN - MS
#define KEYMAX 0x3FFFFFu

__device__ __forceinline__ void atomicMin64(unsigned long long* p, unsigned long long v){
  unsigned long long old = *p;
  while (v < old){
    unsigned long long assumed = old;
    old = atomicCAS(p, assumed, v);
    if (old == assumed) break;
  }
}

// Build 2048-bit adjacency bitmasks, degrees, and init component labels.
__global__ void k_build_bits(const float* __restrict__ A, unsigned long long* __restrict__ bits,
                             unsigned* __restrict__ deg, unsigned* __restrict__ comp){
  int gid = blockIdx.x*blockDim.x + threadIdx.x;   // NN*WW threads
  int i = gid >> 5, w = gid & 31;
  const float* row = A + ((size_t)i << 11) + (w << 6);
  unsigned long long m = 0ull;
  for (int k = 0; k < 64; ++k) if (row[k] > 0.0f) m |= (1ull << k);
  bits[((size_t)i << 5) + w] = m;
  atomicAdd(&deg[i], (unsigned)__popcll(m));
  if (gid < NN) comp[gid] = (unsigned)gid;
}

// Full symmetric key matrix: key22 = round(inter * 2^22 / union), exact int math.
__global__ void k_keymat(const unsigned long long* __restrict__ bits,
                         const unsigned* __restrict__ deg, unsigned* __restrict__ keyM){
  __shared__ unsigned long long bi[64][33];   // +1 pad: avoid 32-way LDS bank conflicts
  __shared__ unsigned long long bj[64][33];
  __shared__ unsigned degi[64], degj[64];
  int ib = blockIdx.x, jb = blockIdx.y;
  int t = threadIdx.x;
  for (int idx = t; idx < 64*32; idx += 256){
    int r = idx >> 5, w = idx & 31;
    bi[r][w] = bits[(((size_t)(ib*64 + r)) << 5) + w];
    bj[r][w] = bits[(((size_t)(jb*64 + r)) << 5) + w];
  }
  if (t < 64){ degi[t] = deg[ib*64 + t]; degj[t] = deg[jb*64 + t]; }
  __syncthreads();
  for (int p = t; p < 4096; p += 256){
    int ii = p >> 6, jj = p & 63;
    int i = ib*64 + ii, j = jb*64 + jj;
    unsigned key = 0u;
    if (i != j){
      unsigned inter = 0;
      #pragma unroll
      for (int w = 0; w < 32; ++w) inter += (unsigned)__popcll(bi[ii][w] & bj[jj][w]);
      unsigned b = degi[ii] + degj[jj] - inter;
      if (b != 0u){
        unsigned long long num = (((unsigned long long)inter) << 22) + (b >> 1);
        unsigned long long q = num / b;
        key = (q > (unsigned long long)KEYMAX) ? KEYMAX : (unsigned)q;
      }
    }
    keyM[((size_t)i << 11) + j] = key;
  }
}

// Per-node best outgoing edge (min 44-bit val) — one wave per row.
// Early-exits once the spanning tree is complete (msf_cnt == NN-1).
__global__ void k_best_node(const unsigned* __restrict__ keyM, const unsigned* __restrict__ comp,
                            unsigned long long* __restrict__ node_best,
                            const unsigned* __restrict__ msf_cnt){
  if (msf_cnt[0] >= (unsigned)(NN-1)) return;
  int gt = blockIdx.x*blockDim.x + threadIdx.x;
  int i = gt >> 6, lane = gt & 63;
  unsigned ci = comp[i];
  const unsigned* row = keyM + ((size_t)i << 11);
  unsigned long long best = ~0ull;
  for (int j = lane; j < NN; j += 64){
    if (j == i) continue;
    if (comp[j] == ci) continue;
    unsigned kp = KEYMAX - row[j];
    unsigned a  = (i < j) ? (unsigned)i : (unsigned)j;
    unsigned b2 = (i < j) ? (unsigned)j : (unsigned)i;
    unsigned long long v = (((unsigned long long)kp) << 22) | (((unsigned long long)a) << 11) | b2;
    if (v < best) best = v;
  }
  for (int off = 32; off; off >>= 1){
    unsigned long long o = __shfl_xor(best, off);
    if (o < best) best = o;
  }
  if (lane == 0) node_best[i] = best;
}

// One Boruvka round: per-component best, hook, 2-cycle break, collect MSF edges,
// pointer-double, relabel. Single block.
__global__ void k_merge(const unsigned long long* __restrict__ node_best,
                        unsigned* __restrict__ comp,
                        unsigned long long* __restrict__ msf, unsigned* __restrict__ msf_cnt){
  if (msf_cnt[0] >= (unsigned)(NN-1)) return;
  __shared__ unsigned long long cbest[NN];
  __shared__ unsigned nxtA[NN], nxtB[NN];
  int t = threadIdx.x;
  for (int c = t; c < NN; c += 256) cbest[c] = ~0ull;
  __syncthreads();
  for (int i = t; i < NN; i += 256) atomicMin64(&cbest[comp[i]], node_best[i]);
  __syncthreads();
  for (int c = t; c < NN; c += 256) nxtA[c] = (unsigned)c;
  __syncthreads();
  for (int c = t; c < NN; c += 256){
    unsigned long long v = cbest[c];
    if (v != ~0ull){
      unsigned a = (unsigned)((v >> 11) & 2047u), b = (unsigned)(v & 2047u);
      unsigned la = comp[a], lb = comp[b];
      if (la != lb) nxtA[c] = (la == (unsigned)c) ? lb : la;
    }
  }
  __syncthreads();
  for (int c = t; c < NN; c += 256){
    unsigned o = nxtA[c];
    if (o != (unsigned)c && nxtA[o] == (unsigned)c && (unsigned)c < o) nxtA[c] = (unsigned)c;
  }
  __syncthreads();
  for (int c = t; c < NN; c += 256){
    if (nxtA[c] != (unsigned)c){
      unsigned idx = atomicAdd(msf_cnt, 1u);
      if (idx < (unsigned)NN) msf[idx] = cbest[c];
    }
  }
  __syncthreads();
  unsigned* s1 = nxtA; unsigned* s2 = nxtB;
  for (int r = 0; r < 11; ++r){
    for (int c = t; c < NN; c += 256) s2[c] = s1[s1[c]];
    __syncthreads();
    unsigned* tmp = s1; s1 = s2; s2 = tmp;
  }
  for (int i = t; i < NN; i += 256) comp[i] = s1[comp[i]];
}

// Sort the 2047 MSF edges, take first TGTM, connected components, labels,
// sizes/scale, cluster member lists (offs + memb).
__global__ void k_final(const unsigned long long* __restrict__ msf, const unsigned* __restrict__ msf_cnt,
                        unsigned* __restrict__ labels_g, float* __restrict__ scale_g,
                        unsigned* __restrict__ offs_g, unsigned* __restrict__ memb_g){
  __shared__ unsigned long long ed[NN];      // later reused as fo/plab
  __shared__ unsigned long long cbest[NN];   // later reused as sizes/scanT
  __shared__ unsigned lab[NN], nxtA[NN], nxtB[NN];
  int t = threadIdx.x;
  unsigned cnt = msf_cnt[0]; if (cnt > (unsigned)NN) cnt = NN;
  for (int i = t; i < NN; i += 256) ed[i] = (i < (int)cnt) ? msf[i] : ~0ull;
  __syncthreads();
  // bitonic sort ascending (44-bit vals unique; pads ~0 sort last)
  for (unsigned k = 2; k <= (unsigned)NN; k <<= 1)
    for (unsigned j = k >> 1; j > 0; j >>= 1){
      for (int i = t; i < NN; i += 256){
        unsigned l = ((unsigned)i) ^ j;
        if (l > (unsigned)i){
          bool up = ((((unsigned)i) & k) == 0u);
          unsigned long long x = ed[i], y = ed[l];
          if ((x > y) == up){ ed[i] = y; ed[l] = x; }
        }
      }
      __syncthreads();
    }
  // CC of first TGTM edges via Boruvka-style hooking (guaranteed <=11 rounds)
  for (int i = t; i < NN; i += 256) lab[i] = (unsigned)i;
  __syncthreads();
  for (int round = 0; round < 11; ++round){
    for (int c = t; c < NN; c += 256) cbest[c] = ~0ull;
    __syncthreads();
    for (int e = t; e < TGTM; e += 256){
      unsigned long long v = ed[e];
      unsigned a = (unsigned)((v >> 11) & 2047u), b = (unsigned)(v & 2047u);
      unsigned la = lab[a], lb = lab[b];
      if (la != lb){ atomicMin64(&cbest[la], v); atomicMin64(&cbest[lb], v); }
    }
    __syncthreads();
    for (int c = t; c < NN; c += 256) nxtA[c] = (unsigned)c;
    __syncthreads();
    for (int c = t; c < NN; c += 256){
      unsigned long long v = cbest[c];
      if (v != ~0ull){
        unsigned a = (unsigned)((v >> 11) & 2047u), b = (unsigned)(v & 2047u);
        unsigned la = lab[a], lb = lab[b];
        if (la != lb) nxtA[c] = (la == (unsigned)c) ? lb : la;
      }
    }
    __syncthreads();
    for (int c = t; c < NN; c += 256){
      unsigned o = nxtA[c];
      if (o != (unsigned)c && nxtA[o] == (unsigned)c && (unsigned)c < o) nxtA[c] = (unsigned)c;
    }
    __syncthreads();
    unsigned* s1 = nxtA; unsigned* s2 = nxtB;
    for (int r = 0; r < 11; ++r){
      for (int c = t; c < NN; c += 256) s2[c] = s1[s1[c]];
      __syncthreads();
      unsigned* tmp = s1; s1 = s2; s2 = tmp;
    }
    for (int i = t; i < NN; i += 256) lab[i] = s1[lab[i]];
    __syncthreads();
  }
  // labels = rank of class by min member; sizes; scale; member lists
  unsigned* fo    = (unsigned*)ed;
  unsigned* plab  = ((unsigned*)ed) + NN;
  unsigned* sizes = (unsigned*)cbest;
  unsigned* scanT = ((unsigned*)cbest) + 1024;
  for (int i = t; i < NN; i += 256) fo[i] = 0xFFFFFFFFu;
  __syncthreads();
  for (int i = t; i < NN; i += 256) atomicMin(&fo[lab[i]], (unsigned)i);
  __syncthreads();
  unsigned loc[8]; unsigned s = 0; int base = t*8;
  for (int k = 0; k < 8; ++k){
    int i = base + k;
    unsigned isf = (fo[lab[i]] == (unsigned)i) ? 1u : 0u;
    loc[k] = s; s += isf;
  }
  scanT[t] = s; __syncthreads();
  for (int off = 1; off < 256; off <<= 1){
    unsigned x = (t >= off) ? scanT[t-off] : 0u;
    __syncthreads();
    scanT[t] += x;
    __syncthreads();
  }
  unsigned excl = scanT[t] - s;
  for (int k = 0; k < 8; ++k) plab[base + k] = excl + loc[k];
  __syncthreads();
  for (int c = t; c < MS; c += 256) sizes[c] = 0u;
  __syncthreads();
  for (int i = t; i < NN; i += 256){
    unsigned L = plab[fo[lab[i]]];
    labels_g[i] = L;
    if (L < (unsigned)MS) atomicAdd(&sizes[L], 1u);
  }
  __syncthreads();
  for (int c = t; c < MS; c += 256) scale_g[c] = 1.0f / sqrtf((float)sizes[c] + 1e-10f);
  // --- member lists: prefix-sum sizes -> offs, scatter node ids by label ---
  unsigned* off_l  = nxtA;          // [0..MS)
  unsigned* cursor = nxtA + 1024;   // [0..MS)
  {
    unsigned a = sizes[2*t], b = sizes[2*t + 1];
    scanT[t] = a + b; __syncthreads();
    for (int o = 1; o < 256; o <<= 1){
      unsigned x = (t >= o) ? scanT[t-o] : 0u;
      __syncthreads();
      scanT[t] += x;
      __syncthreads();
    }
    unsigned ex = scanT[t] - (a + b);
    off_l[2*t]   = ex;
    off_l[2*t+1] = ex + a;
    offs_g[2*t]   = ex;
    offs_g[2*t+1] = ex + a;
    if (t == 0) offs_g[MS] = (unsigned)NN;
  }
  __syncthreads();
  for (int c = t; c < MS; c += 256) cursor[c] = off_l[c];
  __syncthreads();
  for (int i = t; i < NN; i += 256){
    unsigned L = plab[fo[lab[i]]];
    unsigned pos = atomicAdd(&cursor[L], 1u);
    memb_g[pos] = (unsigned)i;
  }
}

__global__ void k_writeP(const unsigned* __restrict__ labels, const float* __restrict__ scale,
                         float* __restrict__ P){
  int i = blockIdx.x*blockDim.x + threadIdx.x;
  if (i < NN){ unsigned L = labels[i]; P[((size_t)i << 9) + L] = scale[L]; }
}

// X_coarse: grid (cluster, d-tile of 128), 128 threads. Member list staged in
// LDS (breaks dependent-load chain); 8 independent partial sums keep 8 X-loads
// in flight -> giant-cluster straggler block ~5us instead of ~1ms.
__global__ void k_coarseX(const float* __restrict__ X, const unsigned* __restrict__ offs,
                          const unsigned* __restrict__ memb, const float* __restrict__ scale,
                          float* __restrict__ Xc){
  __shared__ unsigned mlist[NN];
  int c = blockIdx.x;
  int d = blockIdx.y*128 + threadIdx.x;
  unsigned o = offs[c], e = offs[c+1];
  int nm = (int)(e - o);
  for (int k = threadIdx.x; k < nm; k += 128) mlist[k] = memb[o + k];
  __syncthreads();
  float a0=0.f,a1=0.f,a2=0.f,a3=0.f,a4=0.f,a5=0.f,a6=0.f,a7=0.f;
  int k = 0;
  for (; k + 8 <= nm; k += 8){
    a0 += X[((size_t)mlist[k+0] << 9) + d];
    a1 += X[((size_t)mlist[k+1] << 9) + d];
    a2 += X[((size_t)mlist[k+2] << 9) + d];
    a3 += X[((size_t)mlist[k+3] << 9) + d];
    a4 += X[((size_t)mlist[k+4] << 9) + d];
    a5 += X[((size_t)mlist[k+5] << 9) + d];
    a6 += X[((size_t)mlist[k+6] << 9) + d];
    a7 += X[((size_t)mlist[k+7] << 9) + d];
  }
  for (; k < nm; ++k) a0 += X[((size_t)mlist[k] << 9) + d];
  float acc = ((a0+a1)+(a2+a3)) + ((a4+a5)+(a6+a7));
  Xc[((size_t)c << 9) + d] = acc * scale[c];
}

// A_coarse: one block per cluster; count edges to each cluster in an LDS row
// via members' adjacency bitmasks (A is binary), then write row coalesced.
// Member list staged in LDS to break the memb->bits dependent-load chain.
__global__ void k_coarseA(const unsigned long long* __restrict__ bits,
                          const unsigned* __restrict__ labels,
                          const unsigned* __restrict__ offs, const unsigned* __restrict__ memb,
                          const float* __restrict__ scale, float* __restrict__ Ac){
  __shared__ float row[MS];
  __shared__ unsigned mlist[NN];
  int c = blockIdx.x, t = threadIdx.x;
  for (int j = t; j < MS; j += 256) row[j] = 0.0f;
  unsigned o = offs[c], e = offs[c+1];
  int nm = (int)(e - o);
  for (int k = t; k < nm; k += 256) mlist[k] = memb[o + k];
  __syncthreads();
  for (int idx = t; idx < nm*WW; idx += 256){
    unsigned m = mlist[idx >> 5];
    int w = idx & 31;
    unsigned long long word = bits[((size_t)m << 5) + w];
    while (word){
      int b = __ffsll((long long)word) - 1;
      unsigned j = (unsigned)(w*64 + b);
      atomicAdd(&row[labels[j]], 1.0f);           // LDS atomic
      word &= word - 1ull;
    }
  }
  __syncthreads();
  float sc = scale[c];
  for (int j = t; j < MS; j += 256)
    Ac[((size_t)c << 9) + j] = row[j] * sc * scale[j];
}

extern "C" void kernel_launch(void* const* d_in, const int* in_sizes, int n_in,
                              void* d_out, int out_size, void* d_ws, size_t ws_size,
                              hipStream_t stream) {
  const float* X = (const float*)d_in[0];
  const float* A = (const float*)d_in[1];
  float* out = (float*)d_out;
  char* ws = (char*)d_ws;
  // workspace layout (~16.6 MB, memb/offs overlay dead regions)
  unsigned long long* bits     = (unsigned long long*)(ws + 0x000000);  // 512 KB, live whole run
  unsigned*           deg      = (unsigned*)          (ws + 0x080000);  // 8 KB  (dead after keymat)
  unsigned*           comp     = (unsigned*)          (ws + 0x082000);  // 8 KB  (dead after merges)
  unsigned long long* nodebest = (unsigned long long*)(ws + 0x084000);  // 16 KB (dead after merges)
  unsigned long long* msf      = (unsigned long long*)(ws + 0x088000);  // 16 KB
  unsigned*           msfcnt   = (unsigned*)          (ws + 0x08C000);  // 4 B
  unsigned*           labels   = (unsigned*)          (ws + 0x08D000);  // 8 KB
  float*              scale    = (float*)             (ws + 0x08F000);  // 2 KB
  unsigned*           memb     = (unsigned*)          (ws + 0x084000);  // overlays nodebest (8 KB)
  unsigned*           offs     = (unsigned*)          (ws + 0x080000);  // overlays deg (2052 B)
  unsigned*           keyM     = (unsigned*)          (ws + 0x090000);  // 16 MB

  hipMemsetAsync(deg, 0, NN*sizeof(unsigned), stream);
  hipMemsetAsync(msfcnt, 0, sizeof(unsigned), stream);
  hipMemsetAsync(out + 2*MS*MS, 0, (size_t)NN*MS*sizeof(float), stream);  // P region only

  k_build_bits<<<(NN*WW)/256, 256, 0, stream>>>(A, bits, deg, comp);
  k_keymat<<<dim3(NN/64, NN/64), 256, 0, stream>>>(bits, deg, keyM);
  for (int r = 0; r < 11; ++r){
    k_best_node<<<(NN*64)/256, 256, 0, stream>>>(keyM, comp, nodebest, msfcnt);
    k_merge<<<1, 256, 0, stream>>>(nodebest, comp, msf, msfcnt);
  }
  k_final<<<1, 256, 0, stream>>>(msf, msfcnt, labels, scale, offs, memb);
  k_writeP<<<NN/256, 256, 0, stream>>>(labels, scale, out + 2*MS*MS);
  k_coarseX<<<dim3(MS, DD/128), 128, 0, stream>>>(X, offs, memb, scale, out);
  k_coarseA<<<MS, 256, 0, stream>>>(bits, labels, offs, memb, scale, out + MS*MS);
}

// Round 5
// 473.606 us; speedup vs baseline: 2.6751x; 1.2962x over previous
//
#include <hip/hip_runtime.h>

#define NN 2048
#define WW 32            // u64 words per bitmask row
#define DD 512
#define MS 512           // super nodes
#define TGTM 1536        // merges = NN - MS
#define KEYMAX 0x3FFFFFu
#define BDF 1024         // threads for the single-block kernels

__device__ __forceinline__ void atomicMin64(unsigned long long* p, unsigned long long v){
  unsigned long long old = *p;
  while (v < old){
    unsigned long long assumed = old;
    old = atomicCAS(p, assumed, v);
    if (old == assumed) break;
  }
}

// Build 2048-bit adjacency bitmasks, degrees (wave-reduced, no atomics), comp init.
__global__ void k_build_bits(const float* __restrict__ A, unsigned long long* __restrict__ bits,
                             unsigned* __restrict__ deg, unsigned* __restrict__ comp){
  int gid = blockIdx.x*blockDim.x + threadIdx.x;   // NN*WW threads
  int i = gid >> 5, w = gid & 31;
  const float4* row = (const float4*)(A + ((size_t)i << 11) + (w << 6));
  unsigned long long m = 0ull;
  #pragma unroll
  for (int k = 0; k < 16; ++k){
    float4 v = row[k];
    if (v.x > 0.0f) m |= (1ull << (4*k+0));
    if (v.y > 0.0f) m |= (1ull << (4*k+1));
    if (v.z > 0.0f) m |= (1ull << (4*k+2));
    if (v.w > 0.0f) m |= (1ull << (4*k+3));
  }
  bits[((size_t)i << 5) + w] = m;
  unsigned p = (unsigned)__popcll(m);
  for (int off = 16; off; off >>= 1) p += __shfl_xor(p, off, 32);  // sum within 32-lane row group
  if (w == 0) deg[i] = p;
  if (gid < NN) comp[gid] = (unsigned)gid;
}

// Full symmetric key matrix: key22 = round(inter * 2^22 / union), exact int math.
__global__ void k_keymat(const unsigned long long* __restrict__ bits,
                         const unsigned* __restrict__ deg, unsigned* __restrict__ keyM){
  __shared__ unsigned long long bi[64][33];   // +1 pad: avoid 32-way LDS bank conflicts
  __shared__ unsigned long long bj[64][33];
  __shared__ unsigned degi[64], degj[64];
  int ib = blockIdx.x, jb = blockIdx.y;
  int t = threadIdx.x;
  for (int idx = t; idx < 64*32; idx += 256){
    int r = idx >> 5, w = idx & 31;
    bi[r][w] = bits[(((size_t)(ib*64 + r)) << 5) + w];
    bj[r][w] = bits[(((size_t)(jb*64 + r)) << 5) + w];
  }
  if (t < 64){ degi[t] = deg[ib*64 + t]; degj[t] = deg[jb*64 + t]; }
  __syncthreads();
  for (int p = t; p < 4096; p += 256){
    int ii = p >> 6, jj = p & 63;
    int i = ib*64 + ii, j = jb*64 + jj;
    unsigned key = 0u;
    if (i != j){
      unsigned inter = 0;
      #pragma unroll
      for (int w = 0; w < 32; ++w) inter += (unsigned)__popcll(bi[ii][w] & bj[jj][w]);
      unsigned b = degi[ii] + degj[jj] - inter;
      if (b != 0u){
        unsigned long long num = (((unsigned long long)inter) << 22) + (b >> 1);
        unsigned long long q = num / b;
        key = (q > (unsigned long long)KEYMAX) ? KEYMAX : (unsigned)q;
      }
    }
    keyM[((size_t)i << 11) + j] = key;
  }
}

// Per-node best outgoing edge (min 44-bit val) — one wave per row.
// Early-exits once the spanning tree is complete (msf_cnt == NN-1).
__global__ void k_best_node(const unsigned* __restrict__ keyM, const unsigned* __restrict__ comp,
                            unsigned long long* __restrict__ node_best,
                            const unsigned* __restrict__ msf_cnt){
  if (msf_cnt[0] >= (unsigned)(NN-1)) return;
  int gt = blockIdx.x*blockDim.x + threadIdx.x;
  int i = gt >> 6, lane = gt & 63;
  unsigned ci = comp[i];
  const unsigned* row = keyM + ((size_t)i << 11);
  unsigned long long best = ~0ull;
  for (int j = lane; j < NN; j += 64){
    if (j == i) continue;
    if (comp[j] == ci) continue;
    unsigned kp = KEYMAX - row[j];
    unsigned a  = (i < j) ? (unsigned)i : (unsigned)j;
    unsigned b2 = (i < j) ? (unsigned)j : (unsigned)i;
    unsigned long long v = (((unsigned long long)kp) << 22) | (((unsigned long long)a) << 11) | b2;
    if (v < best) best = v;
  }
  for (int off = 32; off; off >>= 1){
    unsigned long long o = __shfl_xor(best, off);
    if (o < best) best = o;
  }
  if (lane == 0) node_best[i] = best;
}

// One Boruvka round, 1024 threads, convergence-gated pointer doubling.
__global__ void __launch_bounds__(BDF)
k_merge(const unsigned long long* __restrict__ node_best,
        unsigned* __restrict__ comp,
        unsigned long long* __restrict__ msf, unsigned* __restrict__ msf_cnt){
  if (msf_cnt[0] >= (unsigned)(NN-1)) return;
  __shared__ unsigned long long cbest[NN];
  __shared__ unsigned nxtA[NN], nxtB[NN];
  __shared__ int flagS;
  int t = threadIdx.x;
  for (int c = t; c < NN; c += BDF) cbest[c] = ~0ull;
  __syncthreads();
  for (int i = t; i < NN; i += BDF) atomicMin64(&cbest[comp[i]], node_best[i]);
  __syncthreads();
  for (int c = t; c < NN; c += BDF){
    unsigned nx = (unsigned)c;
    unsigned long long v = cbest[c];
    if (v != ~0ull){
      unsigned a = (unsigned)((v >> 11) & 2047u), b = (unsigned)(v & 2047u);
      unsigned la = comp[a], lb = comp[b];
      if (la != lb) nx = (la == (unsigned)c) ? lb : la;
    }
    nxtA[c] = nx;
  }
  __syncthreads();
  for (int c = t; c < NN; c += BDF){
    unsigned o = nxtA[c];
    if (o != (unsigned)c && nxtA[o] == (unsigned)c && (unsigned)c < o) nxtA[c] = (unsigned)c;
  }
  __syncthreads();
  for (int c = t; c < NN; c += BDF){
    if (nxtA[c] != (unsigned)c){
      unsigned idx = atomicAdd(msf_cnt, 1u);
      if (idx < (unsigned)NN) msf[idx] = cbest[c];
    }
  }
  __syncthreads();
  unsigned* s1 = nxtA; unsigned* s2 = nxtB;
  for (int r = 0; r < 11; ++r){
    if (t == 0) flagS = 0;
    __syncthreads();                                   // clear visible
    int ch = 0;
    for (int c = t; c < NN; c += BDF){ unsigned p = s1[c], g = s1[p]; s2[c] = g; ch |= (g != p); }
    if (ch) flagS = 1;
    __syncthreads();                                   // sets visible
    unsigned* tmp = s1; s1 = s2; s2 = tmp;
    int f = flagS;
    __syncthreads();                                   // all read before next clear
    if (!f) break;
  }
  for (int i = t; i < NN; i += BDF) comp[i] = s1[comp[i]];
}

// Sort MSF edges, CC of first TGTM, labels/sizes/scale/member-lists/P — 1024 threads.
__global__ void __launch_bounds__(BDF)
k_final(const unsigned long long* __restrict__ msf, const unsigned* __restrict__ msf_cnt,
        unsigned* __restrict__ labels_g, float* __restrict__ scale_g,
        unsigned* __restrict__ offs_g, unsigned* __restrict__ memb_g,
        float* __restrict__ P){
  __shared__ unsigned long long ed[NN];      // later reused as fo/plab
  __shared__ unsigned long long cbest[NN];   // later reused as sizes/scanT
  __shared__ unsigned lab[NN], nxtA[NN], nxtB[NN];
  __shared__ int flagS;
  int t = threadIdx.x;
  unsigned cnt = msf_cnt[0]; if (cnt > (unsigned)NN) cnt = NN;
  for (int i = t; i < NN; i += BDF) ed[i] = (i < (int)cnt) ? msf[i] : ~0ull;
  __syncthreads();
  // bitonic sort ascending (44-bit vals unique; pads ~0 sort last)
  for (unsigned k = 2; k <= (unsigned)NN; k <<= 1)
    for (unsigned j = k >> 1; j > 0; j >>= 1){
      for (int i = t; i < NN; i += BDF){
        unsigned l = ((unsigned)i) ^ j;
        if (l > (unsigned)i){
          bool up = ((((unsigned)i) & k) == 0u);
          unsigned long long x = ed[i], y = ed[l];
          if ((x > y) == up){ ed[i] = y; ed[l] = x; }
        }
      }
      __syncthreads();
    }
  // CC of first TGTM edges, hooking rounds with convergence early-exit
  for (int i = t; i < NN; i += BDF) lab[i] = (unsigned)i;
  __syncthreads();
  for (int round = 0; round < 11; ++round){
    if (t == 0) flagS = 0;
    for (int c = t; c < NN; c += BDF) cbest[c] = ~0ull;
    __syncthreads();
    for (int e = t; e < TGTM; e += BDF){
      unsigned long long v = ed[e];
      unsigned a = (unsigned)((v >> 11) & 2047u), b = (unsigned)(v & 2047u);
      unsigned la = lab[a], lb = lab[b];
      if (la != lb){ atomicMin64(&cbest[la], v); atomicMin64(&cbest[lb], v); flagS = 1; }
    }
    __syncthreads();
    int active = flagS;
    __syncthreads();                                   // protect flagS reuse below
    if (!active) break;
    for (int c = t; c < NN; c += BDF){
      unsigned nx = (unsigned)c;
      unsigned long long v = cbest[c];
      if (v != ~0ull){
        unsigned a = (unsigned)((v >> 11) & 2047u), b = (unsigned)(v & 2047u);
        unsigned la = lab[a], lb = lab[b];
        if (la != lb) nx = (la == (unsigned)c) ? lb : la;
      }
      nxtA[c] = nx;
    }
    __syncthreads();
    for (int c = t; c < NN; c += BDF){
      unsigned o = nxtA[c];
      if (o != (unsigned)c && nxtA[o] == (unsigned)c && (unsigned)c < o) nxtA[c] = (unsigned)c;
    }
    __syncthreads();
    unsigned* s1 = nxtA; unsigned* s2 = nxtB;
    for (int r = 0; r < 11; ++r){
      if (t == 0) flagS = 0;
      __syncthreads();
      int ch = 0;
      for (int c = t; c < NN; c += BDF){ unsigned p = s1[c], g = s1[p]; s2[c] = g; ch |= (g != p); }
      if (ch) flagS = 1;
      __syncthreads();
      unsigned* tmp = s1; s1 = s2; s2 = tmp;
      int f = flagS;
      __syncthreads();
      if (!f) break;
    }
    for (int i = t; i < NN; i += BDF) lab[i] = s1[lab[i]];
    __syncthreads();
  }
  // labels = rank of class by min member; sizes; scale; member lists; P
  unsigned* fo    = (unsigned*)ed;
  unsigned* plab  = ((unsigned*)ed) + NN;
  unsigned* sizes = (unsigned*)cbest;          // [0,512)
  unsigned* scanT = ((unsigned*)cbest) + 1024; // [1024,2048) — 1024 entries
  for (int i = t; i < NN; i += BDF) fo[i] = 0xFFFFFFFFu;
  __syncthreads();
  for (int i = t; i < NN; i += BDF) atomicMin(&fo[lab[i]], (unsigned)i);
  __syncthreads();
  int i0 = 2*t, i1 = 2*t + 1;
  unsigned f0 = (fo[lab[i0]] == (unsigned)i0) ? 1u : 0u;
  unsigned f1 = (fo[lab[i1]] == (unsigned)i1) ? 1u : 0u;
  unsigned s = f0 + f1;
  scanT[t] = s; __syncthreads();
  for (int off = 1; off < BDF; off <<= 1){
    unsigned x = (t >= off) ? scanT[t-off] : 0u;
    __syncthreads();
    scanT[t] += x;
    __syncthreads();
  }
  unsigned excl = scanT[t] - s;
  plab[i0] = excl; plab[i1] = excl + f0;
  __syncthreads();
  for (int c = t; c < MS; c += BDF) sizes[c] = 0u;
  __syncthreads();
  for (int i = t; i < NN; i += BDF){
    unsigned L = plab[fo[lab[i]]];
    labels_g[i] = L;
    if (L < (unsigned)MS) atomicAdd(&sizes[L], 1u);
  }
  __syncthreads();
  for (int c = t; c < MS; c += BDF) scale_g[c] = 1.0f / sqrtf((float)sizes[c] + 1e-10f);
  // offs: inclusive scan of sizes (512 live entries padded with zeros)
  unsigned* off_l  = nxtA;          // [0..MS)
  unsigned* cursor = nxtA + 1024;   // [0..MS)
  unsigned my = (t < MS) ? sizes[t] : 0u;
  scanT[t] = my; __syncthreads();
  for (int off = 1; off < BDF; off <<= 1){
    unsigned x = (t >= off) ? scanT[t-off] : 0u;
    __syncthreads();
    scanT[t] += x;
    __syncthreads();
  }
  if (t < MS){
    unsigned ex = scanT[t] - my;
    off_l[t] = ex; offs_g[t] = ex;
  }
  if (t == 0) offs_g[MS] = (unsigned)NN;
  __syncthreads();
  for (int c = t; c < MS; c += BDF) cursor[c] = off_l[c];
  __syncthreads();
  for (int i = t; i < NN; i += BDF){
    unsigned L = plab[fo[lab[i]]];
    unsigned pos = atomicAdd(&cursor[L], 1u);
    memb_g[pos] = (unsigned)i;
  }
  // P (P region pre-zeroed by memset)
  for (int i = t; i < NN; i += BDF){
    unsigned L = plab[fo[lab[i]]];
    P[((size_t)i << 9) + L] = 1.0f / sqrtf((float)sizes[L] + 1e-10f);
  }
}

// X_coarse: grid (cluster, d-tile of 128), 128 threads. Member list staged in
// LDS; 8 independent partial sums keep 8 X-loads in flight.
__global__ void k_coarseX(const float* __restrict__ X, const unsigned* __restrict__ offs,
                          const unsigned* __restrict__ memb, const float* __restrict__ scale,
                          float* __restrict__ Xc){
  __shared__ unsigned mlist[NN];
  int c = blockIdx.x;
  int d = blockIdx.y*128 + threadIdx.x;
  unsigned o = offs[c], e = offs[c+1];
  int nm = (int)(e - o);
  for (int k = threadIdx.x; k < nm; k += 128) mlist[k] = memb[o + k];
  __syncthreads();
  float a0=0.f,a1=0.f,a2=0.f,a3=0.f,a4=0.f,a5=0.f,a6=0.f,a7=0.f;
  int k = 0;
  for (; k + 8 <= nm; k += 8){
    a0 += X[((size_t)mlist[k+0] << 9) + d];
    a1 += X[((size_t)mlist[k+1] << 9) + d];
    a2 += X[((size_t)mlist[k+2] << 9) + d];
    a3 += X[((size_t)mlist[k+3] << 9) + d];
    a4 += X[((size_t)mlist[k+4] << 9) + d];
    a5 += X[((size_t)mlist[k+5] << 9) + d];
    a6 += X[((size_t)mlist[k+6] << 9) + d];
    a7 += X[((size_t)mlist[k+7] << 9) + d];
  }
  for (; k < nm; ++k) a0 += X[((size_t)mlist[k] << 9) + d];
  float acc = ((a0+a1)+(a2+a3)) + ((a4+a5)+(a6+a7));
  Xc[((size_t)c << 9) + d] = acc * scale[c];
}

// A_coarse: one block per cluster; LDS histogram over member bitmasks.
__global__ void k_coarseA(const unsigned long long* __restrict__ bits,
                          const unsigned* __restrict__ labels,
                          const unsigned* __restrict__ offs, const unsigned* __restrict__ memb,
                          const float* __restrict__ scale, float* __restrict__ Ac){
  __shared__ float row[MS];
  __shared__ unsigned mlist[NN];
  int c = blockIdx.x, t = threadIdx.x;
  for (int j = t; j < MS; j += 256) row[j] = 0.0f;
  unsigned o = offs[c], e = offs[c+1];
  int nm = (int)(e - o);
  for (int k = t; k < nm; k += 256) mlist[k] = memb[o + k];
  __syncthreads();
  for (int idx = t; idx < nm*WW; idx += 256){
    unsigned m = mlist[idx >> 5];
    int w = idx & 31;
    unsigned long long word = bits[((size_t)m << 5) + w];
    while (word){
      int b = __ffsll((long long)word) - 1;
      unsigned j = (unsigned)(w*64 + b);
      atomicAdd(&row[labels[j]], 1.0f);           // LDS atomic
      word &= word - 1ull;
    }
  }
  __syncthreads();
  float sc = scale[c];
  for (int j = t; j < MS; j += 256)
    Ac[((size_t)c << 9) + j] = row[j] * sc * scale[j];
}

extern "C" void kernel_launch(void* const* d_in, const int* in_sizes, int n_in,
                              void* d_out, int out_size, void* d_ws, size_t ws_size,
                              hipStream_t stream) {
  const float* X = (const float*)d_in[0];
  const float* A = (const float*)d_in[1];
  float* out = (float*)d_out;
  char* ws = (char*)d_ws;
  unsigned long long* bits     = (unsigned long long*)(ws + 0x000000);  // 512 KB, live whole run
  unsigned*           deg      = (unsigned*)          (ws + 0x080000);  // 8 KB  (dead after keymat)
  unsigned*           comp     = (unsigned*)          (ws + 0x082000);  // 8 KB  (dead after merges)
  unsigned long long* nodebest = (unsigned long long*)(ws + 0x084000);  // 16 KB (dead after merges)
  unsigned long long* msf      = (unsigned long long*)(ws + 0x088000);  // 16 KB
  unsigned*           msfcnt   = (unsigned*)          (ws + 0x08C000);  // 4 B
  unsigned*           labels   = (unsigned*)          (ws + 0x08D000);  // 8 KB
  float*              scale    = (float*)             (ws + 0x08F000);  // 2 KB
  unsigned*           memb     = (unsigned*)          (ws + 0x084000);  // overlays nodebest (8 KB)
  unsigned*           offs     = (unsigned*)          (ws + 0x080000);  // overlays deg (2052 B)
  unsigned*           keyM     = (unsigned*)          (ws + 0x090000);  // 16 MB

  hipMemsetAsync(msfcnt, 0, sizeof(unsigned), stream);
  hipMemsetAsync(out + 2*MS*MS, 0, (size_t)NN*MS*sizeof(float), stream);  // P region only

  k_build_bits<<<(NN*WW)/256, 256, 0, stream>>>(A, bits, deg, comp);
  k_keymat<<<dim3(NN/64, NN/64), 256, 0, stream>>>(bits, deg, keyM);
  for (int r = 0; r < 11; ++r){
    k_best_node<<<(NN*64)/256, 256, 0, stream>>>(keyM, comp, nodebest, msfcnt);
    k_merge<<<1, BDF, 0, stream>>>(nodebest, comp, msf, msfcnt);
  }
  k_final<<<1, BDF, 0, stream>>>(msf, msfcnt, labels, scale, offs, memb, out + 2*MS*MS);
  k_coarseX<<<dim3(MS, DD/128), 128, 0, stream>>>(X, offs, memb, scale, out);
  k_coarseA<<<MS, 256, 0, stream>>>(bits, labels, offs, memb, scale, out + MS*MS);
}